// Round 1
// baseline (483.082 us; speedup 1.0000x reference)
//
#include <hip/hip_runtime.h>

#define DEV_INLINE __device__ __forceinline__

constexpr int Nn   = 10000;     // nodes per batch
constexpr int NT   = 20000;     // B*N
constexpr int Me   = 320000;    // template edges
constexpr int Ee   = 2*Me + NT; // 660000 total edges
constexpr float NEG = 0.2f;

DEV_INLINE float leaky(float x){ return x >= 0.f ? x : NEG*x; }

DEV_INLINE void edge_sd(int e, const int* __restrict__ eidx, int& s, int& d){
  if (e < 2*Me){
    int b = (e >= Me) ? 1 : 0;
    int t = e - b*Me;
    s = eidx[t]      + b*Nn;
    d = eidx[Me + t] + b*Nn;
  } else {
    s = e - 2*Me; d = s;
  }
}

// ---------------- style MLP + style @ gw0[64:,:] ----------------
__global__ __launch_bounds__(512) void k_style(const float* __restrict__ z,
    const float* __restrict__ w1, const float* __restrict__ b1,
    const float* __restrict__ w2, const float* __restrict__ b2,
    const float* __restrict__ w3, const float* __restrict__ b3,
    const float* __restrict__ gw0, float* __restrict__ styleW0){
  __shared__ float zl[2][128];
  __shared__ float s1[2][256];
  __shared__ float s2[2][512];
  __shared__ float st[2][128];
  int t = threadIdx.x;
  if (t < 256) zl[t>>7][t&127] = z[t];
  __syncthreads();
  { int b = t>>8, j = t&255; float acc = b1[j];
    for (int k=0;k<128;k++) acc += zl[b][k]*w1[k*256+j];
    s1[b][j] = leaky(acc); }
  __syncthreads();
  { int j = t;
    for (int b=0;b<2;b++){ float acc = b2[j];
      for (int k=0;k<256;k++) acc += s1[b][k]*w2[k*512+j];
      s2[b][j] = leaky(acc); } }
  __syncthreads();
  if (t < 256){ int b=t>>7, j=t&127; float acc=b3[j];
    for (int k=0;k<512;k++) acc += s2[b][k]*w3[k*128+j];
    st[b][j] = acc; }
  __syncthreads();
  if (t < 256){ int b=t>>7, j=t&127; float acc=0.f;
    for (int k=0;k<128;k++) acc += st[b][k]*gw0[(64+k)*128 + j];
    styleW0[b*128+j] = acc; }
}

// ---------------- ht0 = x @ gw0[:64,:] + styleW0[b]  (both batches) ----------------
__global__ __launch_bounds__(256) void k_ht0(const float* __restrict__ x,
    const float* __restrict__ gw0, const float* __restrict__ styleW0,
    float* __restrict__ ht0){
  __shared__ float wl[64][128];
  __shared__ float xl[32][64];
  __shared__ float sw[2][128];
  int t = threadIdx.x;
  for (int i=t; i<64*128; i+=256) wl[i>>7][i&127] = gw0[i];
  if (t < 256) sw[t>>7][t&127] = styleW0[t];
  int row0 = blockIdx.x*32;
  for (int i=t; i<32*64; i+=256){
    int r = i>>6, c = i&63; int gr = row0 + r;
    xl[r][c] = (gr < Nn) ? x[gr*64 + c] : 0.f;
  }
  __syncthreads();
  int c = t & 127, rh = t >> 7;
  float acc[16];
  #pragma unroll
  for (int i=0;i<16;i++) acc[i]=0.f;
  for (int k=0;k<64;k++){
    float w = wl[k][c];
    #pragma unroll
    for (int i=0;i<16;i++) acc[i] += xl[rh+2*i][k]*w;
  }
  float s0 = sw[0][c], s1 = sw[1][c];
  #pragma unroll
  for (int i=0;i<16;i++){
    int gr = row0 + rh + 2*i;
    if (gr < Nn){
      ht0[gr*128 + c]        = acc[i] + s0;
      ht0[(Nn+gr)*128 + c]   = acc[i] + s1;
    }
  }
}

// ---------------- generic tiled matmul: out[M,LDO] = A[M,K] @ W[K,NCOL] ----------------
template<int K, int NCOL, int LDO>
__global__ __launch_bounds__(256) void k_mm(const float* __restrict__ A,
    const float* __restrict__ W, float* __restrict__ out, int Mrows){
  __shared__ float wl[K*NCOL];
  __shared__ float xl[32*K];
  int t = threadIdx.x;
  for (int i=t; i<K*NCOL; i+=256) wl[i] = W[i];
  int row0 = blockIdx.x*32;
  for (int i=t; i<32*K; i+=256){
    int r = i / K, c = i % K; int gr = row0 + r;
    xl[i] = (gr < Mrows) ? A[gr*K + c] : 0.f;
  }
  __syncthreads();
  int c = t & 127, rh = t >> 7;
  if (c < NCOL){
    float acc[16];
    #pragma unroll
    for (int i=0;i<16;i++) acc[i]=0.f;
    for (int k=0;k<K;k++){
      float w = wl[k*NCOL + c];
      #pragma unroll
      for (int i=0;i<16;i++) acc[i] += xl[(rh+2*i)*K + k]*w;
    }
    #pragma unroll
    for (int i=0;i<16;i++){
      int gr = row0 + rh + 2*i;
      if (gr < Mrows) out[gr*LDO + c] = acc[i];
    }
  }
}

// ---------------- per-node attention logits (4 heads x 32) ----------------
__global__ __launch_bounds__(256) void k_al(const float* __restrict__ ht,
    const float* __restrict__ a_s, const float* __restrict__ a_d,
    float* __restrict__ alS, float* __restrict__ alD, int n){
  int g = blockIdx.x*256 + threadIdx.x;
  if (g >= n*4) return;
  int node = g >> 2, h = g & 3;
  const float* row = ht + node*128 + h*32;
  float s = 0.f, dd = 0.f;
  #pragma unroll
  for (int k=0;k<32;k++){ float v = row[k]; s += v*a_s[h*32+k]; dd += v*a_d[h*32+k]; }
  alS[g] = s; alD[g] = dd;
}

// ---------------- per-node attention logits for layer 2 (1 head x 67) ----------------
__global__ __launch_bounds__(256) void k_al2(const float* __restrict__ ht2,
    const float* __restrict__ a_s, const float* __restrict__ a_d,
    float* __restrict__ alS, float* __restrict__ alD, int n){
  int g = blockIdx.x*256 + threadIdx.x;
  if (g >= n) return;
  const float* row = ht2 + g*68;
  float s = 0.f, dd = 0.f;
  #pragma unroll
  for (int k=0;k<67;k++){ float v = row[k]; s += v*a_s[k]; dd += v*a_d[k]; }
  alS[g] = s; alD[g] = dd;
}

// ---------------- CSR build ----------------
__global__ void k_hist(const int* __restrict__ eidx, int* __restrict__ cnt){
  int e = blockIdx.x*256 + threadIdx.x;
  if (e >= Ee) return;
  int s, d; edge_sd(e, eidx, s, d);
  atomicAdd(&cnt[d], 1);
}

__global__ __launch_bounds__(1024) void k_scan(const int* __restrict__ cnt,
    int* __restrict__ row_start, int n){
  __shared__ int buf[1024];
  __shared__ int carry;
  int t = threadIdx.x;
  if (t == 0) carry = 0;
  __syncthreads();
  for (int base = 0; base < n; base += 1024){
    int v = (base + t < n) ? cnt[base + t] : 0;
    buf[t] = v; __syncthreads();
    for (int off = 1; off < 1024; off <<= 1){
      int xval = (t >= off) ? buf[t-off] : 0;
      __syncthreads();
      buf[t] += xval;
      __syncthreads();
    }
    int incl = buf[t];
    if (base + t < n) row_start[base + t] = carry + incl - v;
    __syncthreads();
    if (t == 1023) carry += buf[1023];
    __syncthreads();
  }
  if (t == 0) row_start[n] = carry;
}

__global__ void k_scatter(const int* __restrict__ eidx,
    const int* __restrict__ row_start, int* __restrict__ cursor,
    int* __restrict__ csr){
  int e = blockIdx.x*256 + threadIdx.x;
  if (e >= Ee) return;
  int s, d; edge_sd(e, eidx, s, d);
  int p = row_start[d] + atomicAdd(&cursor[d], 1);
  csr[p] = s;
}

// ---------------- GAT aggregation layer 0/1: softmax + agg + bias + LN + leaky ----------------
__global__ __launch_bounds__(256) void k_gat128(const float* __restrict__ ht,
    const float* __restrict__ alS, const float* __restrict__ alD,
    const int* __restrict__ row_start, const int* __restrict__ csr,
    const float* __restrict__ gb, const float* __restrict__ lng,
    const float* __restrict__ lnb, float* __restrict__ outH, int n){
  int wave = threadIdx.x >> 6, lane = threadIdx.x & 63;
  int d = blockIdx.x*4 + wave;
  if (d >= n) return;
  int c0 = lane, c1 = lane + 64;
  int h0 = c0 >> 5;          // 0 or 1
  int h1 = c1 >> 5;          // 2 or 3
  float4 ald4 = *(const float4*)(alD + d*4);
  int begin = row_start[d], end = row_start[d+1];

  // phase 1: per-head max (lanes split edges, then shuffle-reduce)
  float m0=-1e30f, m1=-1e30f, m2=-1e30f, m3=-1e30f;
  for (int j = begin + lane; j < end; j += 64){
    int s = csr[j];
    float4 as4 = *(const float4*)(alS + s*4);
    m0 = fmaxf(m0, leaky(as4.x + ald4.x));
    m1 = fmaxf(m1, leaky(as4.y + ald4.y));
    m2 = fmaxf(m2, leaky(as4.z + ald4.z));
    m3 = fmaxf(m3, leaky(as4.w + ald4.w));
  }
  #pragma unroll
  for (int off = 32; off; off >>= 1){
    m0 = fmaxf(m0, __shfl_xor(m0, off));
    m1 = fmaxf(m1, __shfl_xor(m1, off));
    m2 = fmaxf(m2, __shfl_xor(m2, off));
    m3 = fmaxf(m3, __shfl_xor(m3, off));
  }
  float mh0 = h0 ? m1 : m0;
  float mh1 = (h1 == 3) ? m3 : m2;
  float ad0 = h0 ? ald4.y : ald4.x;
  float ad1 = (h1 == 3) ? ald4.w : ald4.z;

  // phase 2: column-parallel unnormalized aggregation
  float acc0 = 0.f, acc1 = 0.f, den0 = 0.f, den1 = 0.f;
  for (int j = begin; j < end; j++){
    int s = csr[j];
    float4 as4 = *(const float4*)(alS + s*4);
    float a0 = h0 ? as4.y : as4.x;
    float a1 = (h1 == 3) ? as4.w : as4.z;
    float ex0 = __expf(leaky(a0 + ad0) - mh0);
    float ex1 = __expf(leaky(a1 + ad1) - mh1);
    den0 += ex0; den1 += ex1;
    acc0 += ex0 * ht[s*128 + c0];
    acc1 += ex1 * ht[s*128 + c1];
  }
  float v0 = acc0 / (den0 + 1e-16f) + gb[c0];
  float v1 = acc1 / (den1 + 1e-16f) + gb[c1];

  // LayerNorm over 128 features held by this wave (2 per lane)
  float sum = v0 + v1, sq = v0*v0 + v1*v1;
  #pragma unroll
  for (int off = 32; off; off >>= 1){
    sum += __shfl_xor(sum, off);
    sq  += __shfl_xor(sq,  off);
  }
  float mu  = sum * (1.f/128.f);
  float var = sq  * (1.f/128.f) - mu*mu;
  float inv = rsqrtf(var + 1e-5f);
  float y0 = (v0 - mu)*inv*lng[c0] + lnb[c0];
  float y1 = (v1 - mu)*inv*lng[c1] + lnb[c1];
  outH[d*128 + c0] = leaky(y0);
  outH[d*128 + c1] = leaky(y1);
}

// ---------------- GAT output layer (1 head, 67 cols) + residual + write ----------------
__global__ __launch_bounds__(256) void k_gat_out(const float* __restrict__ ht2,
    const float* __restrict__ alS, const float* __restrict__ alD,
    const int* __restrict__ row_start, const int* __restrict__ csr,
    const float* __restrict__ gb2, const float* __restrict__ x,
    const float* __restrict__ pos, float* __restrict__ out, int n){
  int wave = threadIdx.x >> 6, lane = threadIdx.x & 63;
  int d = blockIdx.x*4 + wave;
  if (d >= n) return;
  int c0 = lane, c1 = lane + 64;
  float ald = alD[d];
  int begin = row_start[d], end = row_start[d+1];
  float m = -1e30f;
  for (int j = begin + lane; j < end; j += 64){
    int s = csr[j];
    m = fmaxf(m, leaky(alS[s] + ald));
  }
  #pragma unroll
  for (int off = 32; off; off >>= 1) m = fmaxf(m, __shfl_xor(m, off));
  float acc0 = 0.f, acc1 = 0.f, den = 0.f;
  for (int j = begin; j < end; j++){
    int s = csr[j];
    float ex = __expf(leaky(alS[s] + ald) - m);
    den += ex;
    acc0 += ex * ht2[s*68 + c0];
    if (c1 < 67) acc1 += ex * ht2[s*68 + c1];
  }
  float idn = 1.f / (den + 1e-16f);
  int i = d % Nn;
  float v0 = acc0*idn + gb2[c0];
  if (c0 < 3) out[NT*64 + d*3 + c0] = pos[i*3 + c0] + v0;
  else        out[d*64 + (c0-3)]    = x[i*64 + (c0-3)] + v0;
  if (c1 < 67){
    float v1 = acc1*idn + gb2[c1];
    out[d*64 + (c1-3)] = x[i*64 + (c1-3)] + v1;
  }
}

extern "C" void kernel_launch(void* const* d_in, const int* in_sizes, int n_in,
                              void* d_out, int out_size, void* d_ws, size_t ws_size,
                              hipStream_t stream){
  const float* z    = (const float*)d_in[0];
  const float* x    = (const float*)d_in[1];
  const float* pos  = (const float*)d_in[2];
  const int*   eidx = (const int*)  d_in[3];
  const float* w1   = (const float*)d_in[4];
  const float* b1   = (const float*)d_in[5];
  const float* w2   = (const float*)d_in[6];
  const float* b2   = (const float*)d_in[7];
  const float* w3   = (const float*)d_in[8];
  const float* b3   = (const float*)d_in[9];
  const float* gw0  = (const float*)d_in[10];
  const float* ga0s = (const float*)d_in[11];
  const float* ga0d = (const float*)d_in[12];
  const float* gb0  = (const float*)d_in[13];
  const float* gw1  = (const float*)d_in[14];
  const float* ga1s = (const float*)d_in[15];
  const float* ga1d = (const float*)d_in[16];
  const float* gb1  = (const float*)d_in[17];
  const float* gw2  = (const float*)d_in[18];
  const float* ga2s = (const float*)d_in[19];
  const float* ga2d = (const float*)d_in[20];
  const float* gb2  = (const float*)d_in[21];
  const float* ln0g = (const float*)d_in[22];
  const float* ln0b = (const float*)d_in[23];
  const float* ln1g = (const float*)d_in[24];
  const float* ln1b = (const float*)d_in[25];
  float* out = (float*)d_out;

  float* ws       = (float*)d_ws;
  float* styleW0  = ws;                  // 256
  float* alS      = ws + 256;            // 80000
  float* alD      = alS + 80000;         // 80000
  float* bufA     = alD + 80000;         // NT*128
  float* bufB     = bufA + NT*128;       // NT*128
  int*   cnt      = (int*)(bufB + NT*128);   // NT
  int*   row_start= cnt + NT;                // NT+1
  int*   csr      = row_start + NT + 1;      // Ee

  // style path
  k_style<<<1, 512, 0, stream>>>(z, w1, b1, w2, b2, w3, b3, gw0, styleW0);

  // CSR by dst (edges fixed per call; rebuilt deterministically in semantics)
  hipMemsetAsync(cnt, 0, NT*sizeof(int), stream);
  k_hist<<<(Ee+255)/256, 256, 0, stream>>>(eidx, cnt);
  k_scan<<<1, 1024, 0, stream>>>(cnt, row_start, NT);
  hipMemsetAsync(cnt, 0, NT*sizeof(int), stream);
  k_scatter<<<(Ee+255)/256, 256, 0, stream>>>(eidx, row_start, cnt, csr);

  // layer 0
  k_ht0<<<(Nn+31)/32, 256, 0, stream>>>(x, gw0, styleW0, bufA);
  k_al<<<(NT*4+255)/256, 256, 0, stream>>>(bufA, ga0s, ga0d, alS, alD, NT);
  k_gat128<<<(NT+3)/4, 256, 0, stream>>>(bufA, alS, alD, row_start, csr,
                                         gb0, ln0g, ln0b, bufB, NT);
  // layer 1
  k_mm<128,128,128><<<(NT+31)/32, 256, 0, stream>>>(bufB, gw1, bufA, NT);
  k_al<<<(NT*4+255)/256, 256, 0, stream>>>(bufA, ga1s, ga1d, alS, alD, NT);
  k_gat128<<<(NT+3)/4, 256, 0, stream>>>(bufA, alS, alD, row_start, csr,
                                         gb1, ln1g, ln1b, bufB, NT);
  // layer 2 (1 head, 67 outputs, fused residual + final write)
  k_mm<128,67,68><<<(NT+31)/32, 256, 0, stream>>>(bufB, gw2, bufA, NT);
  k_al2<<<(NT+255)/256, 256, 0, stream>>>(bufA, ga2s, ga2d, alS, alD, NT);
  k_gat_out<<<(NT+3)/4, 256, 0, stream>>>(bufA, alS, alD, row_start, csr,
                                          gb2, x, pos, out, NT);
}

// Round 2
// 349.803 us; speedup vs baseline: 1.3810x; 1.3810x over previous
//
#include <hip/hip_runtime.h>

#define DEV_INLINE __device__ __forceinline__

constexpr int Nn   = 10000;     // nodes per batch
constexpr int NT   = 20000;     // B*N
constexpr int Me   = 320000;    // template edges
constexpr int Ee   = 2*Me + NT; // 660000 total edges
constexpr int NB   = (NT + 255) / 256;  // scan blocks = 79
constexpr float NEG = 0.2f;

DEV_INLINE float leaky(float x){ return x >= 0.f ? x : NEG*x; }

DEV_INLINE void edge_sd(int e, const int* __restrict__ eidx, int& s, int& d){
  if (e < 2*Me){
    int b = (e >= Me) ? 1 : 0;
    int t = e - b*Me;
    s = eidx[t]      + b*Nn;
    d = eidx[Me + t] + b*Nn;
  } else {
    s = e - 2*Me; d = s;
  }
}

// ---------------- style MLP + style @ gw0[64:,:] ----------------
__global__ __launch_bounds__(512) void k_style(const float* __restrict__ z,
    const float* __restrict__ w1, const float* __restrict__ b1,
    const float* __restrict__ w2, const float* __restrict__ b2,
    const float* __restrict__ w3, const float* __restrict__ b3,
    const float* __restrict__ gw0, float* __restrict__ styleW0){
  __shared__ float zl[2][128];
  __shared__ float s1[2][256];
  __shared__ float s2[2][512];
  __shared__ float st[2][128];
  int t = threadIdx.x;
  if (t < 256) zl[t>>7][t&127] = z[t];
  __syncthreads();
  { int b = t>>8, j = t&255; float acc = b1[j];
    for (int k=0;k<128;k++) acc += zl[b][k]*w1[k*256+j];
    s1[b][j] = leaky(acc); }
  __syncthreads();
  { int j = t;
    for (int b=0;b<2;b++){ float acc = b2[j];
      for (int k=0;k<256;k++) acc += s1[b][k]*w2[k*512+j];
      s2[b][j] = leaky(acc); } }
  __syncthreads();
  if (t < 256){ int b=t>>7, j=t&127; float acc=b3[j];
    for (int k=0;k<512;k++) acc += s2[b][k]*w3[k*128+j];
    st[b][j] = acc; }
  __syncthreads();
  if (t < 256){ int b=t>>7, j=t&127; float acc=0.f;
    for (int k=0;k<128;k++) acc += st[b][k]*gw0[(64+k)*128 + j];
    styleW0[b*128+j] = acc; }
}

// ---------------- ht0 = x @ gw0[:64,:] + styleW0[b]  (both batches) ----------------
__global__ __launch_bounds__(256) void k_ht0(const float* __restrict__ x,
    const float* __restrict__ gw0, const float* __restrict__ styleW0,
    float* __restrict__ ht0){
  __shared__ float wl[64][128];
  __shared__ float xl[32][64];
  __shared__ float sw[2][128];
  int t = threadIdx.x;
  for (int i=t; i<64*128; i+=256) wl[i>>7][i&127] = gw0[i];
  if (t < 256) sw[t>>7][t&127] = styleW0[t];
  int row0 = blockIdx.x*32;
  for (int i=t; i<32*64; i+=256){
    int r = i>>6, c = i&63; int gr = row0 + r;
    xl[r][c] = (gr < Nn) ? x[gr*64 + c] : 0.f;
  }
  __syncthreads();
  int c = t & 127, rh = t >> 7;
  float acc[16];
  #pragma unroll
  for (int i=0;i<16;i++) acc[i]=0.f;
  for (int k=0;k<64;k++){
    float w = wl[k][c];
    #pragma unroll
    for (int i=0;i<16;i++) acc[i] += xl[rh+2*i][k]*w;
  }
  float s0 = sw[0][c], s1 = sw[1][c];
  #pragma unroll
  for (int i=0;i<16;i++){
    int gr = row0 + rh + 2*i;
    if (gr < Nn){
      ht0[gr*128 + c]        = acc[i] + s0;
      ht0[(Nn+gr)*128 + c]   = acc[i] + s1;
    }
  }
}

// ---------------- generic tiled matmul: out[M,LDO] = A[M,K] @ W[K,NCOL] ----------------
template<int K, int NCOL, int LDO>
__global__ __launch_bounds__(256) void k_mm(const float* __restrict__ A,
    const float* __restrict__ W, float* __restrict__ out, int Mrows){
  __shared__ float wl[K*NCOL];
  __shared__ float xl[32*K];
  int t = threadIdx.x;
  for (int i=t; i<K*NCOL; i+=256) wl[i] = W[i];
  int row0 = blockIdx.x*32;
  for (int i=t; i<32*K; i+=256){
    int r = i / K, c = i % K; int gr = row0 + r;
    xl[i] = (gr < Mrows) ? A[gr*K + c] : 0.f;
  }
  __syncthreads();
  int c = t & 127, rh = t >> 7;
  if (c < NCOL){
    float acc[16];
    #pragma unroll
    for (int i=0;i<16;i++) acc[i]=0.f;
    for (int k=0;k<K;k++){
      float w = wl[k*NCOL + c];
      #pragma unroll
      for (int i=0;i<16;i++) acc[i] += xl[(rh+2*i)*K + k]*w;
    }
    #pragma unroll
    for (int i=0;i<16;i++){
      int gr = row0 + rh + 2*i;
      if (gr < Mrows) out[gr*LDO + c] = acc[i];
    }
  }
}

// ---------------- per-node attention logits (4 heads x 32) ----------------
__global__ __launch_bounds__(256) void k_al(const float* __restrict__ ht,
    const float* __restrict__ a_s, const float* __restrict__ a_d,
    float* __restrict__ alS, float* __restrict__ alD, int n){
  int g = blockIdx.x*256 + threadIdx.x;
  if (g >= n*4) return;
  int node = g >> 2, h = g & 3;
  const float* row = ht + node*128 + h*32;
  float s = 0.f, dd = 0.f;
  #pragma unroll
  for (int k=0;k<32;k++){ float v = row[k]; s += v*a_s[h*32+k]; dd += v*a_d[h*32+k]; }
  alS[g] = s; alD[g] = dd;
}

// ---------------- per-node attention logits for layer 2 (1 head x 67) ----------------
__global__ __launch_bounds__(256) void k_al2(const float* __restrict__ ht2,
    const float* __restrict__ a_s, const float* __restrict__ a_d,
    float* __restrict__ alS, float* __restrict__ alD, int n){
  int g = blockIdx.x*256 + threadIdx.x;
  if (g >= n) return;
  const float* row = ht2 + g*68;
  float s = 0.f, dd = 0.f;
  #pragma unroll
  for (int k=0;k<67;k++){ float v = row[k]; s += v*a_s[k]; dd += v*a_d[k]; }
  alS[g] = s; alD[g] = dd;
}

// ---------------- CSR build ----------------
__global__ void k_hist(const int* __restrict__ eidx, int* __restrict__ cnt){
  int e = blockIdx.x*256 + threadIdx.x;
  if (e >= Ee) return;
  int s, d; edge_sd(e, eidx, s, d);
  atomicAdd(&cnt[d], 1);
}

// block-local exclusive scan of cnt -> row_start, block totals -> bsum
__global__ __launch_bounds__(256) void k_scan1(const int* __restrict__ cnt,
    int* __restrict__ row_start, int* __restrict__ bsum){
  __shared__ int wtot[4];
  int t = threadIdx.x, lane = t & 63, wv = t >> 6;
  int i = blockIdx.x*256 + t;
  int v = (i < NT) ? cnt[i] : 0;
  int incl = v;
  #pragma unroll
  for (int d = 1; d < 64; d <<= 1){
    int y = __shfl_up(incl, d);
    if (lane >= d) incl += y;
  }
  if (lane == 63) wtot[wv] = incl;
  __syncthreads();
  int base = 0;
  #pragma unroll
  for (int w = 0; w < 4; w++) if (w < wv) base += wtot[w];
  if (i < NT) row_start[i] = base + incl - v;
  if (t == 255) bsum[blockIdx.x] = base + incl;
}

// single-wave exclusive scan of NB block sums (NB <= 128)
__global__ __launch_bounds__(64) void k_scan2(int* __restrict__ bsum,
    int* __restrict__ row_start){
  int lane = threadIdx.x;
  int v0 = (lane < NB) ? bsum[lane] : 0;
  int v1 = (64 + lane < NB) ? bsum[64 + lane] : 0;
  int i0 = v0, i1 = v1;
  #pragma unroll
  for (int d = 1; d < 64; d <<= 1){
    int y0 = __shfl_up(i0, d), y1 = __shfl_up(i1, d);
    if (lane >= d){ i0 += y0; i1 += y1; }
  }
  int tot0 = __shfl(i0, 63);
  if (lane < NB) bsum[lane] = i0 - v0;
  if (64 + lane < NB) bsum[64 + lane] = tot0 + i1 - v1;
  if (lane == 0) row_start[NT] = Ee;
}

__global__ __launch_bounds__(256) void k_scan3(int* __restrict__ row_start,
    const int* __restrict__ bsum){
  int i = blockIdx.x*256 + threadIdx.x;
  if (i < NT) row_start[i] += bsum[blockIdx.x];
}

__global__ void k_scatter(const int* __restrict__ eidx,
    const int* __restrict__ row_start, int* __restrict__ cursor,
    int* __restrict__ csr){
  int e = blockIdx.x*256 + threadIdx.x;
  if (e >= Ee) return;
  int s, d; edge_sd(e, eidx, s, d);
  int p = row_start[d] + atomicAdd(&cursor[d], 1);
  csr[p] = s;
}

// ---------------- GAT aggregation layer 0/1: softmax + agg + bias + LN + leaky ----------------
__global__ __launch_bounds__(256) void k_gat128(const float* __restrict__ ht,
    const float* __restrict__ alS, const float* __restrict__ alD,
    const int* __restrict__ row_start, const int* __restrict__ csr,
    const float* __restrict__ gb, const float* __restrict__ lng,
    const float* __restrict__ lnb, float* __restrict__ outH, int n){
  int wave = threadIdx.x >> 6, lane = threadIdx.x & 63;
  int d = blockIdx.x*4 + wave;
  if (d >= n) return;
  int c0 = lane, c1 = lane + 64;
  int h0 = c0 >> 5;            // 0 or 1
  bool h13 = (c1 >> 5) == 3;   // head of c1 is 3?
  float4 ald4 = *(const float4*)(alD + d*4);
  int begin = row_start[d], end = row_start[d+1];

  // phase 1: per-head max (lanes split edges, then shuffle-reduce)
  float m0=-1e30f, m1=-1e30f, m2=-1e30f, m3=-1e30f;
  for (int j = begin + lane; j < end; j += 64){
    int s = csr[j];
    float4 as4 = *(const float4*)(alS + s*4);
    m0 = fmaxf(m0, leaky(as4.x + ald4.x));
    m1 = fmaxf(m1, leaky(as4.y + ald4.y));
    m2 = fmaxf(m2, leaky(as4.z + ald4.z));
    m3 = fmaxf(m3, leaky(as4.w + ald4.w));
  }
  #pragma unroll
  for (int off = 32; off; off >>= 1){
    m0 = fmaxf(m0, __shfl_xor(m0, off));
    m1 = fmaxf(m1, __shfl_xor(m1, off));
    m2 = fmaxf(m2, __shfl_xor(m2, off));
    m3 = fmaxf(m3, __shfl_xor(m3, off));
  }
  float mh0 = h0 ? m1 : m0;
  float mh1 = h13 ? m3 : m2;
  float ad0 = h0 ? ald4.y : ald4.x;
  float ad1 = h13 ? ald4.w : ald4.z;

  // phase 2: column-parallel unnormalized aggregation, unrolled x8 for MLP
  const float* __restrict__ ht0p = ht + c0;
  const float* __restrict__ ht1p = ht + c1;
  float acc0 = 0.f, acc1 = 0.f, den0 = 0.f, den1 = 0.f;
  constexpr int U = 8;
  int j = begin;
  for (; j + U <= end; j += U){
    int sidx[U];
    #pragma unroll
    for (int q=0;q<U;q++) sidx[q] = csr[j+q];
    float4 as4[U];
    #pragma unroll
    for (int q=0;q<U;q++) as4[q] = *(const float4*)(alS + sidx[q]*4);
    float hv0[U], hv1[U];
    #pragma unroll
    for (int q=0;q<U;q++){
      hv0[q] = ht0p[sidx[q]*128];
      hv1[q] = ht1p[sidx[q]*128];
    }
    #pragma unroll
    for (int q=0;q<U;q++){
      float a0 = h0  ? as4[q].y : as4[q].x;
      float a1 = h13 ? as4[q].w : as4[q].z;
      float ex0 = __expf(leaky(a0 + ad0) - mh0);
      float ex1 = __expf(leaky(a1 + ad1) - mh1);
      den0 += ex0; den1 += ex1;
      acc0 += ex0 * hv0[q]; acc1 += ex1 * hv1[q];
    }
  }
  for (; j < end; j++){
    int s = csr[j];
    float4 as4 = *(const float4*)(alS + s*4);
    float a0 = h0  ? as4.y : as4.x;
    float a1 = h13 ? as4.w : as4.z;
    float ex0 = __expf(leaky(a0 + ad0) - mh0);
    float ex1 = __expf(leaky(a1 + ad1) - mh1);
    den0 += ex0; den1 += ex1;
    acc0 += ex0 * ht0p[s*128]; acc1 += ex1 * ht1p[s*128];
  }
  float v0 = acc0 / (den0 + 1e-16f) + gb[c0];
  float v1 = acc1 / (den1 + 1e-16f) + gb[c1];

  // LayerNorm over 128 features held by this wave (2 per lane)
  float sum = v0 + v1, sq = v0*v0 + v1*v1;
  #pragma unroll
  for (int off = 32; off; off >>= 1){
    sum += __shfl_xor(sum, off);
    sq  += __shfl_xor(sq,  off);
  }
  float mu  = sum * (1.f/128.f);
  float var = sq  * (1.f/128.f) - mu*mu;
  float inv = rsqrtf(var + 1e-5f);
  float y0 = (v0 - mu)*inv*lng[c0] + lnb[c0];
  float y1 = (v1 - mu)*inv*lng[c1] + lnb[c1];
  outH[d*128 + c0] = leaky(y0);
  outH[d*128 + c1] = leaky(y1);
}

// ---------------- GAT output layer (1 head, 67 cols) + residual + write ----------------
__global__ __launch_bounds__(256) void k_gat_out(const float* __restrict__ ht2,
    const float* __restrict__ alS, const float* __restrict__ alD,
    const int* __restrict__ row_start, const int* __restrict__ csr,
    const float* __restrict__ gb2, const float* __restrict__ x,
    const float* __restrict__ pos, float* __restrict__ out, int n){
  int wave = threadIdx.x >> 6, lane = threadIdx.x & 63;
  int d = blockIdx.x*4 + wave;
  if (d >= n) return;
  int c0 = lane, c1 = lane + 64;
  bool has1 = (c1 < 67);
  float ald = alD[d];
  int begin = row_start[d], end = row_start[d+1];
  float m = -1e30f;
  for (int j = begin + lane; j < end; j += 64){
    int s = csr[j];
    m = fmaxf(m, leaky(alS[s] + ald));
  }
  #pragma unroll
  for (int off = 32; off; off >>= 1) m = fmaxf(m, __shfl_xor(m, off));

  const float* __restrict__ h0p = ht2 + c0;
  const float* __restrict__ h1p = ht2 + c1;
  float acc0 = 0.f, acc1 = 0.f, den = 0.f;
  constexpr int U = 8;
  int j = begin;
  for (; j + U <= end; j += U){
    int sidx[U];
    #pragma unroll
    for (int q=0;q<U;q++) sidx[q] = csr[j+q];
    float av[U];
    #pragma unroll
    for (int q=0;q<U;q++) av[q] = alS[sidx[q]];
    float hv0[U], hv1[U];
    #pragma unroll
    for (int q=0;q<U;q++){
      hv0[q] = h0p[sidx[q]*68];
      hv1[q] = has1 ? h1p[sidx[q]*68] : 0.f;
    }
    #pragma unroll
    for (int q=0;q<U;q++){
      float ex = __expf(leaky(av[q] + ald) - m);
      den += ex;
      acc0 += ex * hv0[q];
      acc1 += ex * hv1[q];
    }
  }
  for (; j < end; j++){
    int s = csr[j];
    float ex = __expf(leaky(alS[s] + ald) - m);
    den += ex;
    acc0 += ex * h0p[s*68];
    if (has1) acc1 += ex * h1p[s*68];
  }
  float idn = 1.f / (den + 1e-16f);
  int i = d % Nn;
  float v0 = acc0*idn + gb2[c0];
  if (c0 < 3) out[NT*64 + d*3 + c0] = pos[i*3 + c0] + v0;
  else        out[d*64 + (c0-3)]    = x[i*64 + (c0-3)] + v0;
  if (has1){
    float v1 = acc1*idn + gb2[c1];
    out[d*64 + (c1-3)] = x[i*64 + (c1-3)] + v1;
  }
}

extern "C" void kernel_launch(void* const* d_in, const int* in_sizes, int n_in,
                              void* d_out, int out_size, void* d_ws, size_t ws_size,
                              hipStream_t stream){
  const float* z    = (const float*)d_in[0];
  const float* x    = (const float*)d_in[1];
  const float* pos  = (const float*)d_in[2];
  const int*   eidx = (const int*)  d_in[3];
  const float* w1   = (const float*)d_in[4];
  const float* b1   = (const float*)d_in[5];
  const float* w2   = (const float*)d_in[6];
  const float* b2   = (const float*)d_in[7];
  const float* w3   = (const float*)d_in[8];
  const float* b3   = (const float*)d_in[9];
  const float* gw0  = (const float*)d_in[10];
  const float* ga0s = (const float*)d_in[11];
  const float* ga0d = (const float*)d_in[12];
  const float* gb0  = (const float*)d_in[13];
  const float* gw1  = (const float*)d_in[14];
  const float* ga1s = (const float*)d_in[15];
  const float* ga1d = (const float*)d_in[16];
  const float* gb1  = (const float*)d_in[17];
  const float* gw2  = (const float*)d_in[18];
  const float* ga2s = (const float*)d_in[19];
  const float* ga2d = (const float*)d_in[20];
  const float* gb2  = (const float*)d_in[21];
  const float* ln0g = (const float*)d_in[22];
  const float* ln0b = (const float*)d_in[23];
  const float* ln1g = (const float*)d_in[24];
  const float* ln1b = (const float*)d_in[25];
  float* out = (float*)d_out;

  float* ws       = (float*)d_ws;
  float* styleW0  = ws;                  // 256
  float* alS      = ws + 256;            // 80000
  float* alD      = alS + 80000;         // 80000
  float* bufA     = alD + 80000;         // NT*128
  float* bufB     = bufA + NT*128;       // NT*128
  int*   cnt      = (int*)(bufB + NT*128);   // NT
  int*   cursor   = cnt + NT;                // NT
  int*   bsum     = cursor + NT;             // NB
  int*   row_start= bsum + ((NB+63)/64)*64;  // NT+1
  int*   csr      = row_start + NT + 1;      // Ee

  // style path
  k_style<<<1, 512, 0, stream>>>(z, w1, b1, w2, b2, w3, b3, gw0, styleW0);

  // CSR by dst
  hipMemsetAsync(cnt, 0, 2*NT*sizeof(int), stream);   // cnt + cursor
  k_hist<<<(Ee+255)/256, 256, 0, stream>>>(eidx, cnt);
  k_scan1<<<NB, 256, 0, stream>>>(cnt, row_start, bsum);
  k_scan2<<<1, 64, 0, stream>>>(bsum, row_start);
  k_scan3<<<NB, 256, 0, stream>>>(row_start, bsum);
  k_scatter<<<(Ee+255)/256, 256, 0, stream>>>(eidx, row_start, cursor, csr);

  // layer 0
  k_ht0<<<(Nn+31)/32, 256, 0, stream>>>(x, gw0, styleW0, bufA);
  k_al<<<(NT*4+255)/256, 256, 0, stream>>>(bufA, ga0s, ga0d, alS, alD, NT);
  k_gat128<<<(NT+3)/4, 256, 0, stream>>>(bufA, alS, alD, row_start, csr,
                                         gb0, ln0g, ln0b, bufB, NT);
  // layer 1
  k_mm<128,128,128><<<(NT+31)/32, 256, 0, stream>>>(bufB, gw1, bufA, NT);
  k_al<<<(NT*4+255)/256, 256, 0, stream>>>(bufA, ga1s, ga1d, alS, alD, NT);
  k_gat128<<<(NT+3)/4, 256, 0, stream>>>(bufA, alS, alD, row_start, csr,
                                         gb1, ln1g, ln1b, bufB, NT);
  // layer 2 (1 head, 67 outputs, fused residual + final write)
  k_mm<128,67,68><<<(NT+31)/32, 256, 0, stream>>>(bufB, gw2, bufA, NT);
  k_al2<<<(NT+255)/256, 256, 0, stream>>>(bufA, ga2s, ga2d, alS, alD, NT);
  k_gat_out<<<(NT+3)/4, 256, 0, stream>>>(bufA, alS, alD, row_start, csr,
                                          gb2, x, pos, out, NT);
}